// Round 1
// baseline (432.649 us; speedup 1.0000x reference)
//
#include <hip/hip_runtime.h>

// FWHT over 2^14 elements per row, 4096 rows, scale 2^-7.
// One block (512 threads) per row. 32 elements/thread held as 8 float4s.
// Stage plan (14 total, order-independent since butterflies on distinct
// bits commute):
//   - load-time register stages: bits e0,e1 (inside float4) + e11,e12,e13
//     (across the 8 float4s j)                              -> 5 stages
//   - LDS phase A: gather slot bits F[2:0] (= e[4:2])       -> 3 stages
//   - LDS phase B: gather slot bits F[5:3] (= e[7:5])       -> 3 stages
//   - LDS phase C: gather slot bits F[8:6] (= e[10:8])      -> 3 stages
// LDS layout: 4096 float4 slots, XOR-swizzled slot^((slot>>3)&7) so every
// phase's 64-lane b128 access spreads 8 lanes per 4-bank group (conflict-
// free baseline). Global loads/stores are float4, lane-contiguous.

#define NF4 4096          // float4 slots per row (16384 floats)
#define SCALE 0.0078125f  // 2^-7

__device__ __forceinline__ int swz(int F) { return F ^ ((F >> 3) & 7); }

__device__ __forceinline__ void bfly2(float4& a, float4& b) {
    float ax = a.x, ay = a.y, az = a.z, aw = a.w;
    float bx = b.x, by = b.y, bz = b.z, bw = b.w;
    a.x = ax + bx; a.y = ay + by; a.z = az + bz; a.w = aw + bw;
    b.x = ax - bx; b.y = ay - by; b.z = az - bz; b.w = aw - bw;
}

// 3 butterfly stages across the 8-element register index
__device__ __forceinline__ void bfly8(float4 v[8]) {
    bfly2(v[0], v[1]); bfly2(v[2], v[3]); bfly2(v[4], v[5]); bfly2(v[6], v[7]);
    bfly2(v[0], v[2]); bfly2(v[1], v[3]); bfly2(v[4], v[6]); bfly2(v[5], v[7]);
    bfly2(v[0], v[4]); bfly2(v[1], v[5]); bfly2(v[2], v[6]); bfly2(v[3], v[7]);
}

// 2 butterfly stages inside a float4 (bits e0, e1)
__device__ __forceinline__ void bfly_inner(float4& t) {
    float a = t.x + t.y, b = t.x - t.y;
    float c = t.z + t.w, d = t.z - t.w;
    t.x = a + c; t.y = b + d; t.z = a - c; t.w = b - d;
}

__global__ __launch_bounds__(512)
void fwht_kernel(const float* __restrict__ in, float* __restrict__ out) {
    __shared__ float4 lds[NF4];

    const int row  = blockIdx.x;
    const int tid  = threadIdx.x;
    const int lane = tid & 63;
    const int w    = tid >> 6;

    const float4* in4  = (const float4*)in  + (size_t)row * NF4;
    float4*       out4 = (float4*)out       + (size_t)row * NF4;

    float4 v[8];

    // ---- load (coalesced: per j, lanes contiguous) + 5 register stages
#pragma unroll
    for (int j = 0; j < 8; ++j) v[j] = in4[tid + 512 * j];
#pragma unroll
    for (int j = 0; j < 8; ++j) bfly_inner(v[j]);   // e0, e1
    bfly8(v);                                       // e11, e12, e13

    // ---- stage into LDS
#pragma unroll
    for (int j = 0; j < 8; ++j) lds[swz(tid + 512 * j)] = v[j];
    __syncthreads();

    // ---- phase A: slot F = g + 8*lane + 512*w  (gather F[2:0] = e[4:2])
    {
        const int base = 8 * lane + 512 * w;
#pragma unroll
        for (int g = 0; g < 8; ++g) v[g] = lds[swz(base + g)];
        bfly8(v);
#pragma unroll
        for (int g = 0; g < 8; ++g) lds[swz(base + g)] = v[g];
    }
    __syncthreads();

    // ---- phase B: slot F = (tid&7) + 8*g + 64*((tid>>3)&7) + 512*w
    //      (gather F[5:3] = e[7:5])
    {
        const int base = (tid & 7) + 64 * ((tid >> 3) & 7) + 512 * w;
#pragma unroll
        for (int g = 0; g < 8; ++g) v[g] = lds[swz(base + 8 * g)];
        bfly8(v);
#pragma unroll
        for (int g = 0; g < 8; ++g) lds[swz(base + 8 * g)] = v[g];
    }
    __syncthreads();

    // ---- phase C: slot F = lane + 64*g + 512*w  (gather F[8:6] = e[10:8])
    //      then scale and store (coalesced: per g, lanes contiguous)
    {
        const int base = lane + 512 * w;
#pragma unroll
        for (int g = 0; g < 8; ++g) v[g] = lds[swz(base + 64 * g)];
        bfly8(v);
#pragma unroll
        for (int g = 0; g < 8; ++g) {
            float4 t = v[g];
            t.x *= SCALE; t.y *= SCALE; t.z *= SCALE; t.w *= SCALE;
            out4[base + 64 * g] = t;
        }
    }
}

extern "C" void kernel_launch(void* const* d_in, const int* in_sizes, int n_in,
                              void* d_out, int out_size, void* d_ws, size_t ws_size,
                              hipStream_t stream) {
    const float* phi = (const float*)d_in[0];
    float* out = (float*)d_out;
    // 4096 rows, one block per row
    fwht_kernel<<<4096, 512, 0, stream>>>(phi, out);
}